// Round 5
// baseline (398.409 us; speedup 1.0000x reference)
//
#include <hip/hip_runtime.h>

// Cost-volume builder:
// out[b, c2, d, h, w] with shape (4, 64, 48, 64, 128) fp32
//   c2 <  32: (w >= d) ? left [b, c2,    h, w    ] : 0
//   c2 >= 32: (w >= d) ? right[b, c2-32, h, w - d] : 0
//
// Write-bound: 402.7 MB out vs 8 MB in. Timed region = re-poison fill
// (~255 us, 1.6 GB @ 6.3 TB/s = plain-store ceiling) + this kernel.
//
// Ladder: R3 (1 store/thread) ~167us. R4/R5/R7 (d-walk, 48 stores/thread at
// 32KB stride; hoisted loads; plain vs nt; XCD-contiguous mapping) all
// ~135us / 3.0 TB/s -- nt, vmcnt-drain, and XCD-locality theories dead.
// R6 (linear order, loads between stores) ~192us: REGRESSION, explained by
// shared in-order vmcnt -- consuming a load issued after a store drains the
// store. So R6 never tested contiguity cleanly.
//
// R8: per-CU store-stream contiguity, the one untested difference vs the
// fill. 512 blocks (2/CU, 8 waves/CU); block = (bc, 24-slab half-d-range)
// sweeping 768 KB CONTIGUOUSLY (d-major, 4KB coalesced steps). Right half
// keeps a sliding {Av,Bv} register window per row and prefetches the next
// q-group's 8 loads BEFORE the current group's 32 stores (loads older in
// vmcnt order -> waiting on them never drains stores). Zeroing window reads
// past the row start reproduces the (w>=d) mask exactly. unroll-1 on the
// d/q loops (pointer bump) so the compiler can't hoist all loads and spill.

#define BB 4
#define CC 32
#define HH 64
#define WW 128
#define DD 48
#define DHALF 24
#define SLAB4 2048              // float4 per (bc,d) slab = 32 KB

typedef float vfloat4 __attribute__((ext_vector_type(4)));

__global__ __launch_bounds__(256) void cost_kernel(
    const float* __restrict__ left,
    const float* __restrict__ right,
    float* __restrict__ out)
{
    const int id    = blockIdx.x;        // 0..511
    const int bc    = id >> 1;           // 0..255
    const int dhalf = id & 1;
    const int d0    = dhalf * DHALF;

    const int t  = threadIdx.x;
    const int k0 = t & 31;               // float4 column within row
    const int hb = t >> 5;               // row base; h = hb + 8*i
    const int w0 = k0 * 4;

    const int  b        = bc >> 6;
    const int  c2       = bc & 63;
    const bool is_right = (c2 >= CC);
    const int  c        = is_right ? (c2 - CC) : c2;
    const float* __restrict__ src = is_right ? right : left;
    const vfloat4* __restrict__ src4 =
        reinterpret_cast<const vfloat4*>(src + (size_t)(b * CC + c) * HH * WW);
    // row h starts at src4[h*32]

    vfloat4* __restrict__ op = reinterpret_cast<vfloat4*>(out)
                             + ((size_t)bc * DD + d0) * SLAB4 + t;
    // store for (dd, i) at op[dd*SLAB4 + i*256]; op bumped as dd advances

    const vfloat4 zero = (vfloat4)(0.0f);

    if (!is_right) {
        // 8 row loads, reused across all 24 d's; then pure store sweep.
        vfloat4 Lv[8];
        #pragma unroll
        for (int i = 0; i < 8; ++i)
            Lv[i] = src4[(hb + 8 * i) * 32 + k0];

        #pragma unroll 1
        for (int dd = 0; dd < DHALF; ++dd, op += SLAB4) {
            const int d = d0 + dd;
            #pragma unroll
            for (int i = 0; i < 8; ++i) {
                vfloat4 o;
                o.x = (w0 + 0 >= d) ? Lv[i].x : 0.0f;
                o.y = (w0 + 1 >= d) ? Lv[i].y : 0.0f;
                o.z = (w0 + 2 >= d) ? Lv[i].z : 0.0f;
                o.w = (w0 + 3 >= d) ? Lv[i].w : 0.0f;
                op[i * 256] = o;
            }
        }
    } else {
        // d = 4q + s. Window for float4 (h, k0) at disparity group q:
        //   Bv = src4[h*32 + k0-q], Av = src4[h*32 + k0-q-1], zero past start.
        const int q0 = d0 >> 2;
        vfloat4 Av[8], Bv[8];
        #pragma unroll
        for (int i = 0; i < 8; ++i) {
            const int base = (hb + 8 * i) * 32;
            int kB = k0 - q0, kA = k0 - q0 - 1;
            vfloat4 vB = src4[base + (kB >= 0 ? kB : 0)];
            vfloat4 vA = src4[base + (kA >= 0 ? kA : 0)];
            Bv[i] = (kB >= 0) ? vB : zero;
            Av[i] = (kA >= 0) ? vA : zero;
        }

        #pragma unroll 1
        for (int qg = 0; qg < DHALF / 4; ++qg, op += 4 * SLAB4) {
            const int q = q0 + qg;

            // Prefetch next window BEFORE this group's stores: loads are
            // older than the stores in vmcnt order, so waiting on them in
            // the next iteration keeps all stores in flight.
            vfloat4 Tv[8];
            #pragma unroll
            for (int i = 0; i < 8; ++i) {
                const int kk = k0 - q - 2;
                vfloat4 v = src4[(hb + 8 * i) * 32 + (kk >= 0 ? kk : 0)];
                Tv[i] = (kk >= 0) ? v : zero;
            }

            #pragma unroll
            for (int s = 0; s < 4; ++s) {
                #pragma unroll
                for (int i = 0; i < 8; ++i) {
                    const vfloat4 B = Bv[i], A = Av[i];
                    vfloat4 o;
                    if      (s == 0) { o = B; }
                    else if (s == 1) { o.x = A.w; o.y = B.x; o.z = B.y; o.w = B.z; }
                    else if (s == 2) { o.x = A.z; o.y = A.w; o.z = B.x; o.w = B.y; }
                    else             { o.x = A.y; o.y = A.z; o.z = A.w; o.w = B.x; }
                    op[s * SLAB4 + i * 256] = o;
                }
            }

            #pragma unroll
            for (int i = 0; i < 8; ++i) { Bv[i] = Av[i]; Av[i] = Tv[i]; }
        }
    }
}

extern "C" void kernel_launch(void* const* d_in, const int* in_sizes, int n_in,
                              void* d_out, int out_size, void* d_ws, size_t ws_size,
                              hipStream_t stream)
{
    const float* left  = (const float*)d_in[0];
    const float* right = (const float*)d_in[1];
    float* out = (float*)d_out;

    cost_kernel<<<dim3(512), dim3(256), 0, stream>>>(left, right, out);
}